// Round 1
// baseline (558.485 us; speedup 1.0000x reference)
//
#include <hip/hip_runtime.h>
#include <math.h>

#define CAT   134
#define NRBF  6
#define ADIM  42
#define NBIL  8
#define MT_PAD 140   // 140 mod 32 = 12 -> b128 bank starts cycle with period 8 lanes

// ---------------------------------------------------------------------------
// Kernel 1: per-angle scalar s_a = dot(a_sbf[a,:], wsum), scatter into sum_s
// ---------------------------------------------------------------------------
__global__ __launch_bounds__(256) void angle_kernel(
    const float* __restrict__ a_sbf, const int* __restrict__ kj_idx,
    const float* __restrict__ W_a, float* __restrict__ sum_s, int A)
{
    __shared__ float wsum[ADIM];
    int tid = threadIdx.x;
    if (tid < ADIM) {
        float s = 0.f;
        #pragma unroll
        for (int b = 0; b < NBIL; ++b) s += W_a[b * ADIM + tid];
        wsum[tid] = s;
    }
    __syncthreads();

    int a = blockIdx.x * 256 + tid;
    if (a >= A) return;

    const float* row = a_sbf + (size_t)a * ADIM;
    float s = 0.f;
    #pragma unroll
    for (int d2 = 0; d2 < ADIM / 2; ++d2) {
        float2 v = *reinterpret_cast<const float2*>(row + d2 * 2);
        s += v.x * wsum[d2 * 2] + v.y * wsum[d2 * 2 + 1];
    }
    atomicAdd(&sum_s[kj_idx[a]], s);
}

// ---------------------------------------------------------------------------
// Kernel 2: per-edge fused  silu(m@Wm^T+b) * (e@We^T)  -> proj -> * sum_s
// Block = 4 waves sharing a 64-edge LDS tile; channels split across waves.
// W_m / b_m / W_e / final_w accessed with wave-uniform addresses -> s_load.
// ---------------------------------------------------------------------------
__global__ __launch_bounds__(256) void edge_kernel(
    const float* __restrict__ m_ji, const float* __restrict__ e_rbf,
    const float* __restrict__ W_m, const float* __restrict__ b_m,
    const float* __restrict__ W_e, const float* __restrict__ final_w,
    const float* __restrict__ sum_s, float* __restrict__ out, int E)
{
    __shared__ float mt[64][MT_PAD];
    __shared__ float projp[4][64][8];

    const int tid  = threadIdx.x;
    const int lane = tid & 63;
    const int wv   = __builtin_amdgcn_readfirstlane(tid >> 6); // wave id, SGPR
    const int e0   = blockIdx.x * 64;

    // ---- stage 64 x 134 m-tile into LDS (coalesced float2) ----
    for (int i = tid; i < 64 * (CAT / 2); i += 256) {
        int r  = i / (CAT / 2);
        int k2 = i - r * (CAT / 2);
        float2 v = make_float2(0.f, 0.f);
        if (e0 + r < E)
            v = *reinterpret_cast<const float2*>(m_ji + (size_t)(e0 + r) * CAT + k2 * 2);
        mt[r][k2 * 2]     = v.x;
        mt[r][k2 * 2 + 1] = v.y;
    }
    __syncthreads();

    const int e = e0 + lane;
    const bool valid = e < E;

    float erbf[NRBF];
    #pragma unroll
    for (int r = 0; r < NRBF; ++r)
        erbf[r] = valid ? e_rbf[(size_t)e * NRBF + r] : 0.f;
    const float ss = valid ? sum_s[e] : 0.f;

    float proj[NRBF] = {0.f, 0.f, 0.f, 0.f, 0.f, 0.f};

    // ---- channel blocks 0..127: wave wv owns channels cb*64 + wv*16 .. +15 ----
    for (int cb = 0; cb < 2; ++cb) {
        const int cbase = cb * 64 + wv * 16;
        float acc[16];
        #pragma unroll
        for (int i = 0; i < 16; ++i) acc[i] = b_m[cbase + i];

        int k = 0;
        for (; k + 4 <= CAT; k += 4) {
            float4 m4 = *reinterpret_cast<const float4*>(&mt[lane][k]);
            #pragma unroll
            for (int i = 0; i < 16; ++i) {
                const float* wrow = W_m + (size_t)(cbase + i) * CAT + k;
                acc[i] += m4.x * wrow[0] + m4.y * wrow[1]
                        + m4.z * wrow[2] + m4.w * wrow[3];
            }
        }
        for (; k < CAT; ++k) {   // k = 132, 133
            float mv = mt[lane][k];
            #pragma unroll
            for (int i = 0; i < 16; ++i)
                acc[i] += mv * W_m[(size_t)(cbase + i) * CAT + k];
        }

        #pragma unroll
        for (int i = 0; i < 16; ++i) {
            const int c = cbase + i;
            const float x  = acc[i];
            const float sm = x / (1.f + __expf(-x));   // silu
            float te = 0.f;
            #pragma unroll
            for (int r = 0; r < NRBF; ++r) te += erbf[r] * W_e[c * NRBF + r];
            const float mae = sm * te;
            #pragma unroll
            for (int r = 0; r < NRBF; ++r) proj[r] += final_w[r * CAT + c] * mae;
        }
    }

    // ---- tail channels 128..133 on wave 0 only ----
    if (wv == 0) {
        float acc[NRBF];
        #pragma unroll
        for (int i = 0; i < NRBF; ++i) acc[i] = b_m[128 + i];

        int k = 0;
        for (; k + 4 <= CAT; k += 4) {
            float4 m4 = *reinterpret_cast<const float4*>(&mt[lane][k]);
            #pragma unroll
            for (int i = 0; i < NRBF; ++i) {
                const float* wrow = W_m + (size_t)(128 + i) * CAT + k;
                acc[i] += m4.x * wrow[0] + m4.y * wrow[1]
                        + m4.z * wrow[2] + m4.w * wrow[3];
            }
        }
        for (; k < CAT; ++k) {
            float mv = mt[lane][k];
            #pragma unroll
            for (int i = 0; i < NRBF; ++i)
                acc[i] += mv * W_m[(size_t)(128 + i) * CAT + k];
        }

        #pragma unroll
        for (int i = 0; i < NRBF; ++i) {
            const int c = 128 + i;
            const float x  = acc[i];
            const float sm = x / (1.f + __expf(-x));
            float te = 0.f;
            #pragma unroll
            for (int r = 0; r < NRBF; ++r) te += erbf[r] * W_e[c * NRBF + r];
            const float mae = sm * te;
            #pragma unroll
            for (int r = 0; r < NRBF; ++r) proj[r] += final_w[r * CAT + c] * mae;
        }
    }

    // ---- cross-wave proj reduction + scale + store ----
    #pragma unroll
    for (int r = 0; r < NRBF; ++r) projp[wv][lane][r] = proj[r];
    __syncthreads();

    if (wv == 0 && valid) {
        #pragma unroll
        for (int r = 0; r < NRBF; ++r) {
            float v = (projp[0][lane][r] + projp[1][lane][r] +
                       projp[2][lane][r] + projp[3][lane][r]) * ss;
            out[(size_t)e * NRBF + r] = v;
        }
    }
}

// ---------------------------------------------------------------------------
extern "C" void kernel_launch(void* const* d_in, const int* in_sizes, int n_in,
                              void* d_out, int out_size, void* d_ws, size_t ws_size,
                              hipStream_t stream)
{
    const float* m_ji    = (const float*)d_in[0];
    // d_in[1] nbr_list, d_in[2] angle_list: unused by the reference math
    const float* e_rbf   = (const float*)d_in[3];
    const float* a_sbf   = (const float*)d_in[4];
    const int*   kj_idx  = (const int*)  d_in[5];
    const float* W_m     = (const float*)d_in[6];
    const float* b_m     = (const float*)d_in[7];
    const float* W_e     = (const float*)d_in[8];
    const float* W_a     = (const float*)d_in[9];
    const float* final_w = (const float*)d_in[10];
    float* out = (float*)d_out;

    const int E = in_sizes[0] / CAT;
    const int A = in_sizes[5];

    float* sum_s = (float*)d_ws;  // E floats of scratch
    hipMemsetAsync(sum_s, 0, (size_t)E * sizeof(float), stream);

    angle_kernel<<<(A + 255) / 256, 256, 0, stream>>>(a_sbf, kj_idx, W_a, sum_s, A);
    edge_kernel<<<(E + 63) / 64, 256, 0, stream>>>(m_ji, e_rbf, W_m, b_m, W_e,
                                                   final_w, sum_s, out, E);
}